// Round 1
// baseline (763.220 us; speedup 1.0000x reference)
//
#include <hip/hip_runtime.h>

// CTC loss forward (sum reduction), matching the JAX reference.
// Shapes fixed by setup_inputs(): T=1000, B=64, V=512, S=100.
// Structure: one wave (64 lanes) per batch element; lane l owns extended
// states 4l..4l+3 in registers. Base-2 log domain (native v_exp/v_log).
// Only cross-lane dep per step: prev lane's a3 (even states are BLANK and
// never take the 2-skip, so a[s-2] is never cross-lane-by-2).

#define NEGF (-1e30f)

constexpr int CT_T = 1000;
constexpr int CT_B = 64;
constexpr int CT_V = 512;
constexpr int CT_S = 100;
constexpr int CT_Se = 2 * CT_S + 1;  // 201
constexpr float LOG2E = 1.4426950408889634f;
constexpr float LN2   = 0.6931471805599453f;

#if __has_builtin(__builtin_amdgcn_exp2f) && __has_builtin(__builtin_amdgcn_logf)
__device__ __forceinline__ float fexp2(float x) { return __builtin_amdgcn_exp2f(x); }
__device__ __forceinline__ float flog2(float x) { return __builtin_amdgcn_logf(x); }  // v_log_f32 = log2
#else
__device__ __forceinline__ float fexp2(float x) { return exp2f(x); }
__device__ __forceinline__ float flog2(float x) { return log2f(x); }
#endif

// log2(2^x + 2^y)
__device__ __forceinline__ float lae2_b2(float x, float y) {
    float m = fmaxf(x, y);
    float d = fminf(x, y) - m;           // <= 0
    return m + flog2(1.0f + fexp2(d));
}
// log2(2^x + 2^y + 2^z)
__device__ __forceinline__ float lae3_b2(float x, float y, float z) {
    float m = fmaxf(fmaxf(x, y), z);
    float s = fexp2(x - m) + fexp2(y - m) + fexp2(z - m);
    return m + flog2(s);
}

__global__ __launch_bounds__(64) void ctc_alpha(
    const float* __restrict__ logp,      // (T, B, V) natural-log probs
    const int*   __restrict__ in_len,    // (B,)
    const int*   __restrict__ tgt,       // (B, S)
    const int*   __restrict__ tgt_len,   // (B,)
    float*       __restrict__ loss_ws)   // (B,) per-sample loss out
{
    const int b    = blockIdx.x;
    const int lane = threadIdx.x;
    const int Tin  = in_len[b];
    const int Lt   = tgt_len[b];
    const int ext_len = 2 * Lt + 1;
    const int* tg = tgt + b * CT_S;

    const int s0 = 4 * lane, s1 = s0 + 1, s2 = s0 + 2, s3 = s0 + 3;

    // Labels for odd states (even states are BLANK=1). Clamp indices for
    // lanes past Se (they stay invalid forever anyway).
    const int i1 = min((s1 - 1) >> 1, CT_S - 1);
    const int i3 = min((s3 - 1) >> 1, CT_S - 1);
    const int c1 = tg[i1];
    const int c3 = tg[i3];
    const bool skip1 = (s1 >= 3) && (s1 < CT_Se) && (c1 != tg[max(i1 - 1, 0)]);
    const bool skip3 = (s3 >= 3) && (s3 < CT_Se) && (c3 != tg[max(i3 - 1, 0)]);
    const bool v0 = s0 < ext_len, v1 = s1 < ext_len;
    const bool v2 = s2 < ext_len, v3 = s3 < ext_len;

    const float* row0 = logp + (long long)b * CT_V;
    const long long stride = (long long)CT_B * CT_V;

    // alpha in base-2 log domain
    float a0 = NEGF, a1 = NEGF, a2 = NEGF, a3 = NEGF;
    if (lane == 0) {
        a0 = row0[1] * LOG2E;                       // ext[0] = BLANK
        if (ext_len > 1) a1 = row0[c1] * LOG2E;     // ext[1] = targets[0]
    }

    // Emit prefetch slots: per lane 3 gathers (blank col shared by s0,s2).
    float3 E0, E1, E2, E3;
    auto ld = [&](float3& e, int t) {
        int tt = min(t, CT_T - 1);
        const float* r = row0 + (long long)tt * stride;
        e.x = r[1]  * LOG2E;
        e.y = r[c1] * LOG2E;
        e.z = r[c3] * LOG2E;
    };
    auto step = [&](const float3& e) {
        float pa3 = __shfl_up(a3, 1);        // alpha[4l-1] from lane l-1
        if (lane == 0) pa3 = NEGF;
        float z1 = skip1 ? pa3 : NEGF;       // alpha[s1-2] = alpha[4l-1]
        float z3 = skip3 ? a1  : NEGF;       // alpha[s3-2] = alpha[4l+1]
        float n0 = v0 ? lae2_b2(a0, pa3)    + e.x : NEGF;
        float n1 = v1 ? lae3_b2(a1, a0, z1) + e.y : NEGF;
        float n2 = v2 ? lae2_b2(a2, a1)     + e.x : NEGF;
        float n3 = v3 ? lae3_b2(a3, a2, z3) + e.z : NEGF;
        a0 = n0; a1 = n1; a2 = n2; a3 = n3;
    };

    ld(E0, 1); ld(E1, 2); ld(E2, 3); ld(E3, 4);
    for (int t = 1; t < Tin; t += 4) {
        step(E0); ld(E0, t + 4);
        if (t + 1 < Tin) { step(E1); ld(E1, t + 5); }
        if (t + 2 < Tin) { step(E2); ld(E2, t + 6); }
        if (t + 3 < Tin) { step(E3); ld(E3, t + 7); }
    }

    // loglik = logaddexp(alpha[2L], alpha[max(2L-1,0)])
    const int last = 2 * Lt;
    const int prev = max(last - 1, 0);
    const int lr = last & 3, ll = last >> 2;       // uniform per block
    float av = (lr == 0) ? a0 : (lr == 1) ? a1 : (lr == 2) ? a2 : a3;
    float a_last = __shfl(av, ll);
    const int pr = prev & 3, pl = prev >> 2;
    float pv = (pr == 0) ? a0 : (pr == 1) ? a1 : (pr == 2) ? a2 : a3;
    float a_prev = __shfl(pv, pl);

    float loglik = lae2_b2(a_last, a_prev) * LN2;  // back to natural log
    float loss = (loglik < 0.5f * NEGF) ? 0.0f : -loglik;  // zero_infinity
    if (lane == 0) loss_ws[b] = loss;
}

__global__ __launch_bounds__(64) void ctc_sum(const float* __restrict__ loss_ws,
                                              float* __restrict__ out)
{
    float v = loss_ws[threadIdx.x];   // B == 64 == one wave
    #pragma unroll
    for (int o = 32; o > 0; o >>= 1) v += __shfl_down(v, o);
    if (threadIdx.x == 0) out[0] = v;
}

extern "C" void kernel_launch(void* const* d_in, const int* in_sizes, int n_in,
                              void* d_out, int out_size, void* d_ws, size_t ws_size,
                              hipStream_t stream) {
    const float* logp    = (const float*)d_in[0];
    const int*   in_len  = (const int*)d_in[1];
    const int*   tgt     = (const int*)d_in[2];
    const int*   tgt_len = (const int*)d_in[3];
    float* ws  = (float*)d_ws;
    float* out = (float*)d_out;

    hipLaunchKernelGGL(ctc_alpha, dim3(CT_B), dim3(64), 0, stream,
                       logp, in_len, tgt, tgt_len, ws);
    hipLaunchKernelGGL(ctc_sum, dim3(1), dim3(64), 0, stream, ws, out);
}

// Round 2
// 437.407 us; speedup vs baseline: 1.7449x; 1.7449x over previous
//
#include <hip/hip_runtime.h>

// CTC loss forward (sum reduction). Shapes fixed: T=1000, B=64, V=512, S=100.
// Two-phase:
//   1) ctc_emit: parallel gather emit[b][t][s] = logp[t][b][ext[b][s]]*log2(e)
//      into workspace, s-contiguous (204 floats/row, float4-aligned).
//   2) ctc_alpha: one wave per b; lane l owns states 4l..4l+3 in registers;
//      16-deep float4 prefetch ring hides HBM latency; per-step cross-lane
//      dep is a single __shfl_up (even states are BLANK => no 2-skip across
//      a distance-2 lane boundary).
// Base-2 log domain so logaddexp uses native v_exp_f32/v_log_f32.

#define NEGF (-1e30f)

constexpr int CT_T  = 1000;
constexpr int CT_B  = 64;
constexpr int CT_V  = 512;
constexpr int CT_S  = 100;
constexpr int CT_Se = 2 * CT_S + 1;   // 201
constexpr int CT_R  = 204;            // padded row (multiple of 4)
constexpr float LOG2E = 1.4426950408889634f;
constexpr float LN2   = 0.6931471805599453f;

constexpr size_t EMIT_FLOATS = (size_t)CT_B * CT_T * CT_R;   // 13,056,000
constexpr size_t EMIT_BYTES  = EMIT_FLOATS * 4;              // 52,224,000
constexpr size_t WS_NEEDED   = EMIT_BYTES + 256 * 4;

#if __has_builtin(__builtin_amdgcn_exp2f) && __has_builtin(__builtin_amdgcn_logf)
__device__ __forceinline__ float fexp2(float x) { return __builtin_amdgcn_exp2f(x); }
__device__ __forceinline__ float flog2(float x) { return __builtin_amdgcn_logf(x); }
#else
__device__ __forceinline__ float fexp2(float x) { return exp2f(x); }
__device__ __forceinline__ float flog2(float x) { return log2f(x); }
#endif

// log2(2^x + 2^y)
__device__ __forceinline__ float lae2_b2(float x, float y) {
    float m = fmaxf(x, y);
    float d = fminf(x, y) - m;
    return m + flog2(1.0f + fexp2(d));
}
// log2(2^x + 2^y + 2^z)
__device__ __forceinline__ float lae3_b2(float x, float y, float z) {
    float m = fmaxf(fmaxf(x, y), z);
    float s = fexp2(x - m) + fexp2(y - m) + fexp2(z - m);
    return m + flog2(s);
}

// ---------------- Phase 1: emit gather ----------------
__global__ __launch_bounds__(256) void ctc_emit(
    const float* __restrict__ logp,   // (T, B, V)
    const int*   __restrict__ tgt,    // (B, S)
    float*       __restrict__ emit)   // (B, T, 204)
{
    const int t = blockIdx.x;
    const int b = blockIdx.y;
    const int s = threadIdx.x;
    if (s >= CT_R) return;
    int col = 1;  // BLANK
    if ((s & 1) && s < CT_Se) col = tgt[b * CT_S + (s >> 1)];
    float v = logp[((long long)t * CT_B + b) * CT_V + col] * LOG2E;
    emit[((long long)b * CT_T + t) * CT_R + s] = v;
}

// ---------------- Phase 2: recursion ----------------
__global__ __launch_bounds__(64) void ctc_alpha(
    const float* __restrict__ logp,
    const int*   __restrict__ in_len,
    const int*   __restrict__ tgt,
    const int*   __restrict__ tgt_len,
    const float* __restrict__ emit,    // (B, T, 204) base-2 emits
    float*       __restrict__ loss_ws)
{
    const int b    = blockIdx.x;
    const int lane = threadIdx.x;
    const int Tin  = in_len[b];
    const int Lt   = tgt_len[b];
    const int ext_len = 2 * Lt + 1;
    const int* tg = tgt + b * CT_S;

    const int s0 = 4 * lane, s1 = s0 + 1, s3 = s0 + 3;

    const int i1 = min((s1 - 1) >> 1, CT_S - 1);
    const int i3 = min((s3 - 1) >> 1, CT_S - 1);
    const int c1 = tg[i1];
    const int c3 = tg[i3];
    const bool skip1 = (s1 >= 3) && (s1 < CT_Se) && (c1 != tg[max(i1 - 1, 0)]);
    const bool skip3 = (s3 >= 3) && (s3 < CT_Se) && (c3 != tg[max(i3 - 1, 0)]);
    const bool v0 = s0 < ext_len, v1 = s1 < ext_len;
    const bool v2 = (s0 + 2) < ext_len, v3 = s3 < ext_len;

    const float* row0 = logp + (long long)b * CT_V;
    const float* em   = emit + (long long)b * CT_T * CT_R;

    float a0 = NEGF, a1 = NEGF, a2 = NEGF, a3 = NEGF;
    if (lane == 0) {
        a0 = row0[1] * LOG2E;
        if (ext_len > 1) a1 = row0[c1] * LOG2E;
    }

    auto ldE = [&](int t) -> float4 {
        int tt = min(t, CT_T - 1);
        if (lane < 51)
            return *(const float4*)(em + (long long)tt * CT_R + 4 * lane);
        return make_float4(NEGF, NEGF, NEGF, NEGF);
    };

    auto step = [&](const float4& e) {
        float pa3 = __shfl_up(a3, 1);          // alpha[4l-1]
        if (lane == 0) pa3 = NEGF;
        float z1 = skip1 ? pa3 : NEGF;
        float z3 = skip3 ? a1  : NEGF;
        float n2 = v2 ? lae2_b2(a2, a1)     + e.z : NEGF;  // no shfl dep
        float n3 = v3 ? lae3_b2(a3, a2, z3) + e.w : NEGF;  // no shfl dep
        float n0 = v0 ? lae2_b2(a0, pa3)    + e.x : NEGF;
        float n1 = v1 ? lae3_b2(a1, a0, z1) + e.y : NEGF;
        a0 = n0; a1 = n1; a2 = n2; a3 = n3;
    };

    constexpr int D = 16;   // prefetch depth: D*step_time > HBM latency
    float4 E[D];
    #pragma unroll
    for (int i = 0; i < D; ++i) E[i] = ldE(1 + i);

    for (int t = 1; t < Tin; t += D) {
        #pragma unroll
        for (int i = 0; i < D; ++i) {
            if (t + i < Tin) { step(E[i]); E[i] = ldE(t + i + D); }
        }
    }

    const int last = 2 * Lt;
    const int prev = max(last - 1, 0);
    const int lr = last & 3, ll = last >> 2;
    float av = (lr == 0) ? a0 : (lr == 1) ? a1 : (lr == 2) ? a2 : a3;
    float a_last = __shfl(av, ll);
    const int pr = prev & 3, pl = prev >> 2;
    float pv = (pr == 0) ? a0 : (pr == 1) ? a1 : (pr == 2) ? a2 : a3;
    float a_prev = __shfl(pv, pl);

    float loglik = lae2_b2(a_last, a_prev) * LN2;
    float loss = (loglik < 0.5f * NEGF) ? 0.0f : -loglik;
    if (lane == 0) loss_ws[b] = loss;
}

// ---------------- Fallback (R1 single-pass, no workspace) ----------------
__global__ __launch_bounds__(64) void ctc_alpha_fb(
    const float* __restrict__ logp, const int* __restrict__ in_len,
    const int* __restrict__ tgt, const int* __restrict__ tgt_len,
    float* __restrict__ loss_ws)
{
    const int b = blockIdx.x, lane = threadIdx.x;
    const int Tin = in_len[b], Lt = tgt_len[b];
    const int ext_len = 2 * Lt + 1;
    const int* tg = tgt + b * CT_S;
    const int s0 = 4 * lane, s1 = s0 + 1, s3 = s0 + 3;
    const int i1 = min((s1 - 1) >> 1, CT_S - 1);
    const int i3 = min((s3 - 1) >> 1, CT_S - 1);
    const int c1 = tg[i1], c3 = tg[i3];
    const bool skip1 = (s1 >= 3) && (s1 < CT_Se) && (c1 != tg[max(i1 - 1, 0)]);
    const bool skip3 = (s3 >= 3) && (s3 < CT_Se) && (c3 != tg[max(i3 - 1, 0)]);
    const bool v0 = s0 < ext_len, v1 = s1 < ext_len;
    const bool v2 = (s0 + 2) < ext_len, v3 = s3 < ext_len;
    const float* row0 = logp + (long long)b * CT_V;
    const long long stride = (long long)CT_B * CT_V;
    float a0 = NEGF, a1 = NEGF, a2 = NEGF, a3 = NEGF;
    if (lane == 0) {
        a0 = row0[1] * LOG2E;
        if (ext_len > 1) a1 = row0[c1] * LOG2E;
    }
    float3 E0, E1, E2, E3;
    auto ld = [&](float3& e, int t) {
        int tt = min(t, CT_T - 1);
        const float* r = row0 + (long long)tt * stride;
        e.x = r[1] * LOG2E; e.y = r[c1] * LOG2E; e.z = r[c3] * LOG2E;
    };
    auto step = [&](const float3& e) {
        float pa3 = __shfl_up(a3, 1);
        if (lane == 0) pa3 = NEGF;
        float z1 = skip1 ? pa3 : NEGF;
        float z3 = skip3 ? a1 : NEGF;
        float n0 = v0 ? lae2_b2(a0, pa3)    + e.x : NEGF;
        float n1 = v1 ? lae3_b2(a1, a0, z1) + e.y : NEGF;
        float n2 = v2 ? lae2_b2(a2, a1)     + e.x : NEGF;
        float n3 = v3 ? lae3_b2(a3, a2, z3) + e.z : NEGF;
        a0 = n0; a1 = n1; a2 = n2; a3 = n3;
    };
    ld(E0, 1); ld(E1, 2); ld(E2, 3); ld(E3, 4);
    for (int t = 1; t < Tin; t += 4) {
        step(E0); ld(E0, t + 4);
        if (t + 1 < Tin) { step(E1); ld(E1, t + 5); }
        if (t + 2 < Tin) { step(E2); ld(E2, t + 6); }
        if (t + 3 < Tin) { step(E3); ld(E3, t + 7); }
    }
    const int last = 2 * Lt, prev = max(last - 1, 0);
    const int lr = last & 3, ll = last >> 2;
    float av = (lr == 0) ? a0 : (lr == 1) ? a1 : (lr == 2) ? a2 : a3;
    float a_last = __shfl(av, ll);
    const int pr = prev & 3, pl = prev >> 2;
    float pv = (pr == 0) ? a0 : (pr == 1) ? a1 : (pr == 2) ? a2 : a3;
    float a_prev = __shfl(pv, pl);
    float loglik = lae2_b2(a_last, a_prev) * LN2;
    float loss = (loglik < 0.5f * NEGF) ? 0.0f : -loglik;
    if (lane == 0) loss_ws[b] = loss;
}

__global__ __launch_bounds__(64) void ctc_sum(const float* __restrict__ loss_ws,
                                              float* __restrict__ out)
{
    float v = loss_ws[threadIdx.x];
    #pragma unroll
    for (int o = 32; o > 0; o >>= 1) v += __shfl_down(v, o);
    if (threadIdx.x == 0) out[0] = v;
}

extern "C" void kernel_launch(void* const* d_in, const int* in_sizes, int n_in,
                              void* d_out, int out_size, void* d_ws, size_t ws_size,
                              hipStream_t stream) {
    const float* logp    = (const float*)d_in[0];
    const int*   in_len  = (const int*)d_in[1];
    const int*   tgt     = (const int*)d_in[2];
    const int*   tgt_len = (const int*)d_in[3];
    float* out = (float*)d_out;

    if (ws_size >= WS_NEEDED) {
        float* emit    = (float*)d_ws;
        float* loss_ws = emit + EMIT_FLOATS;
        hipLaunchKernelGGL(ctc_emit, dim3(CT_T, CT_B), dim3(256), 0, stream,
                           logp, tgt, emit);
        hipLaunchKernelGGL(ctc_alpha, dim3(CT_B), dim3(64), 0, stream,
                           logp, in_len, tgt, tgt_len, emit, loss_ws);
        hipLaunchKernelGGL(ctc_sum, dim3(1), dim3(64), 0, stream, loss_ws, out);
    } else {
        float* loss_ws = (float*)d_ws;   // needs only 256 B
        hipLaunchKernelGGL(ctc_alpha_fb, dim3(CT_B), dim3(64), 0, stream,
                           logp, in_len, tgt, tgt_len, loss_ws);
        hipLaunchKernelGGL(ctc_sum, dim3(1), dim3(64), 0, stream, loss_ws, out);
    }
}

// Round 3
// 323.857 us; speedup vs baseline: 2.3567x; 1.3506x over previous
//
#include <hip/hip_runtime.h>

// CTC loss forward (sum reduction). Shapes fixed: T=1000, B=64, V=512, S=100.
// Phase 1 (ctc_emit): per (b,t) store row-max-normalized LINEAR probs
//   em[b][t][s] = 2^(logp[t][b][ext[s]]*log2e - M2[b][t]),  M2 = row max (base-2)
// Phase 2 (ctc_alpha): one wave per b, lane l owns states 4l..4l+3; linear
//   recursion (adds/muls only), 16-deep unconditional register prefetch ring,
//   wave-max renorm every 8 steps; exact loglik via  log2(a)+sum(M2)+sum(renorm).

#define NEGF (-1e30f)

constexpr int CT_T  = 1000;
constexpr int CT_B  = 64;
constexpr int CT_V  = 512;
constexpr int CT_S  = 100;
constexpr int CT_Se = 2 * CT_S + 1;   // 201
constexpr int CT_R  = 204;            // emit row stride (floats), 16B aligned
constexpr float LOG2E = 1.4426950408889634f;
constexpr float LN2   = 0.6931471805599453f;

constexpr size_t EMIT_FLOATS = (size_t)CT_B * CT_T * CT_R;   // 13,056,000
constexpr size_t M2_FLOATS   = (size_t)CT_B * CT_T;          // 64,000
constexpr size_t WS_NEEDED   = (EMIT_FLOATS + M2_FLOATS + 256) * 4;

#if __has_builtin(__builtin_amdgcn_exp2f) && __has_builtin(__builtin_amdgcn_logf)
__device__ __forceinline__ float fexp2(float x) { return __builtin_amdgcn_exp2f(x); }
__device__ __forceinline__ float flog2(float x) { return __builtin_amdgcn_logf(x); }
__device__ __forceinline__ float frcp(float x)  { return __builtin_amdgcn_rcpf(x); }
#else
__device__ __forceinline__ float fexp2(float x) { return exp2f(x); }
__device__ __forceinline__ float flog2(float x) { return log2f(x); }
__device__ __forceinline__ float frcp(float x)  { return 1.0f / x; }
#endif

__device__ __forceinline__ float lae2_b2(float x, float y) {
    float m = fmaxf(x, y);
    float d = fminf(x, y) - m;
    return m + flog2(1.0f + fexp2(d));
}
__device__ __forceinline__ float lae3_b2(float x, float y, float z) {
    float m = fmaxf(fmaxf(x, y), z);
    float s = fexp2(x - m) + fexp2(y - m) + fexp2(z - m);
    return m + flog2(s);
}

// ---------------- Phase 1: normalized-linear emit ----------------
__global__ __launch_bounds__(256) void ctc_emit(
    const float* __restrict__ logp,   // (T, B, V) natural-log probs
    const int*   __restrict__ tgt,    // (B, S)
    float*       __restrict__ em,     // (B, T, 204) normalized linear probs
    float*       __restrict__ m2)     // (B, T) base-2 row max
{
    __shared__ float rows[8][CT_V];
    const int b    = blockIdx.y;
    const int t0   = blockIdx.x * 8;
    const int wave = threadIdx.x >> 6;
    const int lane = threadIdx.x & 63;
    const int r0   = 2 * wave;               // this wave's two rows

    // column per handled state s = lane + 64k
    int cols[4];
    #pragma unroll
    for (int k = 0; k < 4; ++k) {
        int s = lane + 64 * k;
        int c = -1;                           // pad
        if (s < CT_Se) c = (s & 1) ? tgt[b * CT_S + (s >> 1)] : 1;
        cols[k] = c;
    }

    float M2r[2];
    #pragma unroll
    for (int j = 0; j < 2; ++j) {
        const int r = r0 + j, t = t0 + r;
        const float* src = logp + ((long long)t * CT_B + b) * CT_V;
        float4 x0 = *(const float4*)(src + 8 * lane);
        float4 x1 = *(const float4*)(src + 8 * lane + 4);
        *(float4*)(&rows[r][8 * lane])     = x0;
        *(float4*)(&rows[r][8 * lane + 4]) = x1;
        float lm = fmaxf(fmaxf(fmaxf(x0.x, x0.y), fmaxf(x0.z, x0.w)),
                         fmaxf(fmaxf(x1.x, x1.y), fmaxf(x1.z, x1.w)));
        #pragma unroll
        for (int off = 32; off; off >>= 1) lm = fmaxf(lm, __shfl_xor(lm, off));
        M2r[j] = lm * LOG2E;
        if (lane == 0) m2[b * CT_T + t] = M2r[j];
    }
    __syncthreads();

    #pragma unroll
    for (int j = 0; j < 2; ++j) {
        const int r = r0 + j, t = t0 + r;
        float* dst = em + ((long long)b * CT_T + t) * CT_R;
        #pragma unroll
        for (int k = 0; k < 4; ++k) {
            int s = lane + 64 * k;
            if (s < CT_R) {
                float v = 0.0f;
                if (cols[k] >= 0)
                    v = fexp2(rows[r][cols[k]] * LOG2E - M2r[j]);
                dst[s] = v;
            }
        }
    }
}

// ---------------- Phase 2: linear-domain recursion ----------------
__global__ __launch_bounds__(64) void ctc_alpha(
    const int*   __restrict__ in_len,
    const int*   __restrict__ tgt,
    const int*   __restrict__ tgt_len,
    const float* __restrict__ em,      // (B, T, 204)
    const float* __restrict__ m2,      // (B, T)
    float*       __restrict__ loss_ws)
{
    const int b    = blockIdx.x;
    const int lane = threadIdx.x;
    const int Tin  = in_len[b];
    const int Lt   = tgt_len[b];
    const int ext_len = 2 * Lt + 1;
    const int* tg = tgt + b * CT_S;

    const int s0 = 4 * lane, s1 = s0 + 1, s3 = s0 + 3;
    const int i1 = min((s1 - 1) >> 1, CT_S - 1);
    const int i3 = min((s3 - 1) >> 1, CT_S - 1);
    const int c1 = tg[i1];
    const int c3 = tg[i3];
    const bool skip1 = (s1 >= 3) && (s1 < CT_Se) && (c1 != tg[max(i1 - 1, 0)]);
    const bool skip3 = (s3 >= 3) && (s3 < CT_Se) && (c3 != tg[max(i3 - 1, 0)]);
    const bool v0 = s0 < ext_len, v1 = s1 < ext_len;
    const bool v2 = (s0 + 2) < ext_len, v3 = s3 < ext_len;

    const float* emb = em + (long long)b * CT_T * CT_R;
    const float* m2b = m2 + b * CT_T;

    // init from t=0 row (already normalized by M2[0])
    float a0 = 0.f, a1 = 0.f, a2 = 0.f, a3 = 0.f;
    if (lane == 0) {
        a0 = emb[0];
        if (ext_len > 1) a1 = emb[1];
    }
    float pa3 = 0.f;              // alpha[4l-1] from lane l-1
    float mS  = m2b[0];           // running base-2 scale (uniform)
    float rs  = 0.f;              // renorm scale accumulator (uniform)

    constexpr int D = 16;
    float4 E[D]; float M2E[D];
    auto ldE = [&](int i, int t) {
        int tt = min(t, CT_T - 1);
        if (lane < 51)
            E[i] = *(const float4*)(emb + (long long)tt * CT_R + 4 * lane);
        else
            E[i] = make_float4(0.f, 0.f, 0.f, 0.f);
        M2E[i] = m2b[tt];
    };
    #pragma unroll
    for (int i = 0; i < D; ++i) ldE(i, 1 + i);

    for (int t = 1; t < CT_T; t += D) {
        #pragma unroll
        for (int i = 0; i < D; ++i) {
            float4 e = E[i];
            float M2v = M2E[i];
            // mask states beyond this sample's ext_len
            e.x = v0 ? e.x : 0.f;
            e.y = v1 ? e.y : 0.f;
            e.z = v2 ? e.z : 0.f;
            e.w = v3 ? e.w : 0.f;
            float n0 = (a0 + pa3) * e.x;
            float n1 = (a1 + a0 + (skip1 ? pa3 : 0.f)) * e.y;
            float n2 = (a2 + a1) * e.z;
            float n3 = (a3 + a2 + (skip3 ? a1 : 0.f)) * e.w;
            bool ok = (t + i) < Tin;            // wave-uniform freeze
            if (ok) { a0 = n0; a1 = n1; a2 = n2; a3 = n3; mS += M2v; }
            pa3 = __shfl_up(a3, 1);
            if (lane == 0) pa3 = 0.f;
            ldE(i, t + i + D);                  // unconditional: keep ring live
            if ((i & 7) == 7) {
                // wave-max renorm (value-preserving: rs compensates)
                float lm = fmaxf(fmaxf(a0, a1), fmaxf(a2, a3));
                #pragma unroll
                for (int off = 1; off < 64; off <<= 1)
                    lm = fmaxf(lm, __shfl_xor(lm, off));
                if (lm > 0.f) {
                    float sc = frcp(lm);
                    rs += flog2(lm);
                    a0 *= sc; a1 *= sc; a2 *= sc; a3 *= sc; pa3 *= sc;
                }
            }
        }
    }

    const int last = 2 * Lt;
    const int prev = max(last - 1, 0);
    const int lr = last & 3, ll = last >> 2;
    float av = (lr == 0) ? a0 : (lr == 1) ? a1 : (lr == 2) ? a2 : a3;
    float a_last = __shfl(av, ll);
    const int pr = prev & 3, pl = prev >> 2;
    float pv = (pr == 0) ? a0 : (pr == 1) ? a1 : (pr == 2) ? a2 : a3;
    float a_prev = __shfl(pv, pl);

    float sum = a_last + a_prev;
    float loss = 0.0f;
    if (sum > 0.f) loss = -(flog2(sum) + mS + rs) * LN2;
    if (lane == 0) loss_ws[b] = loss;
}

// ---------------- Fallback (log-domain single pass, tiny ws) ----------------
__global__ __launch_bounds__(64) void ctc_alpha_fb(
    const float* __restrict__ logp, const int* __restrict__ in_len,
    const int* __restrict__ tgt, const int* __restrict__ tgt_len,
    float* __restrict__ loss_ws)
{
    const int b = blockIdx.x, lane = threadIdx.x;
    const int Tin = in_len[b], Lt = tgt_len[b];
    const int ext_len = 2 * Lt + 1;
    const int* tg = tgt + b * CT_S;
    const int s0 = 4 * lane, s1 = s0 + 1, s3 = s0 + 3;
    const int i1 = min((s1 - 1) >> 1, CT_S - 1);
    const int i3 = min((s3 - 1) >> 1, CT_S - 1);
    const int c1 = tg[i1], c3 = tg[i3];
    const bool skip1 = (s1 >= 3) && (s1 < CT_Se) && (c1 != tg[max(i1 - 1, 0)]);
    const bool skip3 = (s3 >= 3) && (s3 < CT_Se) && (c3 != tg[max(i3 - 1, 0)]);
    const bool v0 = s0 < ext_len, v1 = s1 < ext_len;
    const bool v2 = (s0 + 2) < ext_len, v3 = s3 < ext_len;
    const float* row0 = logp + (long long)b * CT_V;
    const long long stride = (long long)CT_B * CT_V;
    float a0 = NEGF, a1 = NEGF, a2 = NEGF, a3 = NEGF;
    if (lane == 0) {
        a0 = row0[1] * LOG2E;
        if (ext_len > 1) a1 = row0[c1] * LOG2E;
    }
    float3 E0, E1, E2, E3;
    auto ld = [&](float3& e, int t) {
        int tt = min(t, CT_T - 1);
        const float* r = row0 + (long long)tt * stride;
        e.x = r[1] * LOG2E; e.y = r[c1] * LOG2E; e.z = r[c3] * LOG2E;
    };
    auto step = [&](const float3& e) {
        float pa3 = __shfl_up(a3, 1);
        if (lane == 0) pa3 = NEGF;
        float z1 = skip1 ? pa3 : NEGF;
        float z3 = skip3 ? a1 : NEGF;
        float n0 = v0 ? lae2_b2(a0, pa3)    + e.x : NEGF;
        float n1 = v1 ? lae3_b2(a1, a0, z1) + e.y : NEGF;
        float n2 = v2 ? lae2_b2(a2, a1)     + e.x : NEGF;
        float n3 = v3 ? lae3_b2(a3, a2, z3) + e.z : NEGF;
        a0 = n0; a1 = n1; a2 = n2; a3 = n3;
    };
    ld(E0, 1); ld(E1, 2); ld(E2, 3); ld(E3, 4);
    for (int t = 1; t < Tin; t += 4) {
        step(E0); ld(E0, t + 4);
        if (t + 1 < Tin) { step(E1); ld(E1, t + 5); }
        if (t + 2 < Tin) { step(E2); ld(E2, t + 6); }
        if (t + 3 < Tin) { step(E3); ld(E3, t + 7); }
    }
    const int last = 2 * Lt, prev = max(last - 1, 0);
    const int lr = last & 3, ll = last >> 2;
    float av = (lr == 0) ? a0 : (lr == 1) ? a1 : (lr == 2) ? a2 : a3;
    float a_last = __shfl(av, ll);
    const int pr = prev & 3, pl = prev >> 2;
    float pv = (pr == 0) ? a0 : (pr == 1) ? a1 : (pr == 2) ? a2 : a3;
    float a_prev = __shfl(pv, pl);
    float loglik = lae2_b2(a_last, a_prev) * LN2;
    float loss = (loglik < 0.5f * NEGF) ? 0.0f : -loglik;
    if (lane == 0) loss_ws[b] = loss;
}

__global__ __launch_bounds__(64) void ctc_sum(const float* __restrict__ loss_ws,
                                              float* __restrict__ out)
{
    float v = loss_ws[threadIdx.x];
    #pragma unroll
    for (int o = 32; o > 0; o >>= 1) v += __shfl_down(v, o);
    if (threadIdx.x == 0) out[0] = v;
}

extern "C" void kernel_launch(void* const* d_in, const int* in_sizes, int n_in,
                              void* d_out, int out_size, void* d_ws, size_t ws_size,
                              hipStream_t stream) {
    const float* logp    = (const float*)d_in[0];
    const int*   in_len  = (const int*)d_in[1];
    const int*   tgt     = (const int*)d_in[2];
    const int*   tgt_len = (const int*)d_in[3];
    float* out = (float*)d_out;

    if (ws_size >= WS_NEEDED) {
        float* em      = (float*)d_ws;
        float* m2      = em + EMIT_FLOATS;
        float* loss_ws = m2 + M2_FLOATS;
        hipLaunchKernelGGL(ctc_emit, dim3(CT_T / 8, CT_B), dim3(256), 0, stream,
                           logp, tgt, em, m2);
        hipLaunchKernelGGL(ctc_alpha, dim3(CT_B), dim3(64), 0, stream,
                           in_len, tgt, tgt_len, em, m2, loss_ws);
        hipLaunchKernelGGL(ctc_sum, dim3(1), dim3(64), 0, stream, loss_ws, out);
    } else {
        float* loss_ws = (float*)d_ws;
        hipLaunchKernelGGL(ctc_alpha_fb, dim3(CT_B), dim3(64), 0, stream,
                           logp, in_len, tgt, tgt_len, loss_ws);
        hipLaunchKernelGGL(ctc_sum, dim3(1), dim3(64), 0, stream, loss_ws, out);
    }
}

// Round 4
// 289.575 us; speedup vs baseline: 2.6357x; 1.1184x over previous
//
#include <hip/hip_runtime.h>

// CTC loss forward (sum reduction). Shapes fixed: T=1000, B=64, V=512, S=100.
// Phase 1 (ctc_emit): pure gather, em[b][t][s] = bf16( p(ext[s]) * 2^10 ),
//   p = exp(logp). Fixed scale 2^10 (no row max), exactly compensated later.
// Phase 2 (ctc_alpha): one wave per b (launch_bounds(64,1) -> scheduler keeps
//   the prefetch ring live); lane l owns states 4l..4l+3; linear recursion
//   (adds/muls only, one __shfl_up per step); explicit double-buffered 16-deep
//   register prefetch; wave-max renorm every 16 steps with exact rs
//   compensation. loglik = ln2 * (log2(sum) + rs - 10*Tin).

#define NEGF (-1e30f)

constexpr int CT_T  = 1000;
constexpr int CT_B  = 64;
constexpr int CT_V  = 512;
constexpr int CT_S  = 100;
constexpr int CT_Se = 2 * CT_S + 1;   // 201
constexpr int CT_RB = 208;            // bf16 row stride (elements) = 416 B
constexpr float LOG2E = 1.4426950408889634f;
constexpr float LN2   = 0.6931471805599453f;
constexpr float EMIT_SHIFT = 10.0f;   // fixed base-2 scale per frame

constexpr size_t EM_SHORTS = (size_t)CT_B * CT_T * CT_RB;  // 13,312,000
constexpr size_t EM_BYTES  = EM_SHORTS * 2;                // 26,624,000
constexpr size_t WS_NEEDED = EM_BYTES + 1024;

#if __has_builtin(__builtin_amdgcn_exp2f) && __has_builtin(__builtin_amdgcn_logf)
__device__ __forceinline__ float fexp2(float x) { return __builtin_amdgcn_exp2f(x); }
__device__ __forceinline__ float flog2(float x) { return __builtin_amdgcn_logf(x); }
__device__ __forceinline__ float frcp(float x)  { return __builtin_amdgcn_rcpf(x); }
#else
__device__ __forceinline__ float fexp2(float x) { return exp2f(x); }
__device__ __forceinline__ float flog2(float x) { return log2f(x); }
__device__ __forceinline__ float frcp(float x)  { return 1.0f / x; }
#endif

__device__ __forceinline__ float lae2_b2(float x, float y) {
    float m = fmaxf(x, y);
    float d = fminf(x, y) - m;
    return m + flog2(1.0f + fexp2(d));
}
__device__ __forceinline__ float lae3_b2(float x, float y, float z) {
    float m = fmaxf(fmaxf(x, y), z);
    float s = fexp2(x - m) + fexp2(y - m) + fexp2(z - m);
    return m + flog2(s);
}

// ---------------- Phase 1: gather + scale + bf16 ----------------
__global__ __launch_bounds__(256) void ctc_emit(
    const float* __restrict__ logp,    // (T, B, V)
    const int*   __restrict__ tgt,     // (B, S)
    unsigned short* __restrict__ em)   // (B, T, 208) bf16
{
    const int b    = blockIdx.y;
    const int t    = blockIdx.x * 4 + (threadIdx.x >> 6);
    const int lane = threadIdx.x & 63;
    if (lane >= 52) return;
    const int* tg = tgt + b * CT_S;
    const int s0 = 4 * lane;
    const int i1 = min(s0 >> 1, CT_S - 1);        // label idx for s0+1
    const int i3 = min((s0 + 2) >> 1, CT_S - 1);  // label idx for s0+3
    const int c1 = tg[i1], c3 = tg[i3];
    const float* src = logp + ((long long)t * CT_B + b) * CT_V;
    float pb = src[1];
    float p1 = src[c1];
    float p3 = src[c3];
    auto enc = [&](float lp, bool valid) -> unsigned short {
        if (!valid) return 0;
        float q = fexp2(fmaf(lp, LOG2E, EMIT_SHIFT));
        unsigned u = __float_as_uint(q);
        return (unsigned short)((u + 0x7fff + ((u >> 16) & 1)) >> 16);  // RNE
    };
    ushort4 o;
    o.x = enc(pb, s0     < CT_Se);
    o.y = enc(p1, s0 + 1 < CT_Se);
    o.z = enc(pb, s0 + 2 < CT_Se);
    o.w = enc(p3, s0 + 3 < CT_Se);
    *(ushort4*)(em + ((long long)b * CT_T + t) * CT_RB + 4 * lane) = o;
}

// ---------------- Phase 2: linear recursion, deep prefetch ----------------
__global__ __launch_bounds__(64, 1) void ctc_alpha(
    const int* __restrict__ in_len,
    const int* __restrict__ tgt,
    const int* __restrict__ tgt_len,
    const unsigned short* __restrict__ em,   // (B, T, 208) bf16
    float* __restrict__ loss_ws)
{
    const int b    = blockIdx.x;
    const int lane = threadIdx.x;
    const int Tin  = in_len[b];
    const int Lt   = tgt_len[b];
    const int ext_len = 2 * Lt + 1;
    const int* tg = tgt + b * CT_S;

    const int s0 = 4 * lane, s1 = s0 + 1, s3 = s0 + 3;
    const int i1 = min((s1 - 1) >> 1, CT_S - 1);
    const int i3 = min((s3 - 1) >> 1, CT_S - 1);
    const int c1 = tg[i1];
    const int c3 = tg[i3];
    const float sk1 = ((s1 >= 3) && (s1 < CT_Se) && (c1 != tg[max(i1 - 1, 0)])) ? 1.f : 0.f;
    const float sk3 = ((s3 >= 3) && (s3 < CT_Se) && (c3 != tg[max(i3 - 1, 0)])) ? 1.f : 0.f;
    const bool v0 = s0 < ext_len, v1 = s1 < ext_len;
    const bool v2 = (s0 + 2) < ext_len, v3 = s3 < ext_len;

    const unsigned short* emb = em + (long long)b * CT_T * CT_RB;
    const int ll = min(lane, 51);   // clamp: lanes 52..63 re-read lane 51 (masked)

    float a0 = 0.f, a1 = 0.f, a2 = 0.f, a3 = 0.f, pa3 = 0.f;
    if (lane == 0) {
        unsigned d0 = *(const unsigned*)emb;        // s=0 (lo), s=1 (hi) of row 0
        a0 = __uint_as_float(d0 << 16);
        if (ext_len > 1) a1 = __uint_as_float(d0 & 0xffff0000u);
    }
    float rs = 0.f;   // accumulated renorm log2-scale (wave-uniform)

    uint2 A[16], Bv[16];
    auto addr = [&](int t) -> const uint2* {
        int tt = min(t, CT_T - 1);
        return (const uint2*)(emb + (long long)tt * CT_RB + 4 * ll);
    };
    auto pf = [&](uint2* buf, int tb) {
        #pragma unroll
        for (int i = 0; i < 16; ++i) buf[i] = *addr(tb + i);
    };
    auto run16 = [&](const uint2* buf, int tb) {
        #pragma unroll
        for (int i = 0; i < 16; ++i) {
            uint2 d = buf[i];
            float ex = v0 ? __uint_as_float(d.x << 16)          : 0.f;
            float ey = v1 ? __uint_as_float(d.x & 0xffff0000u)  : 0.f;
            float ez = v2 ? __uint_as_float(d.y << 16)          : 0.f;
            float ew = v3 ? __uint_as_float(d.y & 0xffff0000u)  : 0.f;
            float n0 = (a0 + pa3) * ex;
            float n1 = fmaf(sk1, pa3, a1 + a0) * ey;
            float n2 = (a2 + a1) * ez;
            float n3 = fmaf(sk3, a1, a3 + a2) * ew;
            if (tb + i < Tin) { a0 = n0; a1 = n1; a2 = n2; a3 = n3; }  // uniform
            pa3 = __shfl_up(a3, 1);
            if (lane == 0) pa3 = 0.f;
        }
        // wave-max renorm, exactly compensated via rs
        float lm = fmaxf(fmaxf(a0, a1), fmaxf(a2, a3));
        #pragma unroll
        for (int off = 1; off < 64; off <<= 1) lm = fmaxf(lm, __shfl_xor(lm, off));
        if (lm > 0.f) {
            float sc = frcp(lm);
            rs -= flog2(sc);
            a0 *= sc; a1 *= sc; a2 *= sc; a3 *= sc; pa3 *= sc;
        }
    };

    pf(A, 1);
    for (int t = 1; ; t += 32) {
        pf(Bv, t + 16);       // loads for next half issued before this half's compute
        run16(A, t);
        pf(A, t + 32);
        run16(Bv, t + 16);
        if (t + 32 >= Tin) break;   // all later steps frozen anyway
    }

    const int last = 2 * Lt;
    const int prev = max(last - 1, 0);
    const int lr = last & 3, lidx = last >> 2;
    float av = (lr == 0) ? a0 : (lr == 1) ? a1 : (lr == 2) ? a2 : a3;
    float a_last = __shfl(av, lidx);
    const int pr = prev & 3, pidx = prev >> 2;
    float pv = (pr == 0) ? a0 : (pr == 1) ? a1 : (pr == 2) ? a2 : a3;
    float a_prev = __shfl(pv, pidx);

    float sum = a_last + a_prev;
    float loss = 0.f;
    if (sum > 0.f)
        loss = -(flog2(sum) + rs - EMIT_SHIFT * (float)Tin) * LN2;
    if (lane == 0) loss_ws[b] = loss;
}

// ---------------- Fallback (log-domain single pass, tiny ws) ----------------
__global__ __launch_bounds__(64) void ctc_alpha_fb(
    const float* __restrict__ logp, const int* __restrict__ in_len,
    const int* __restrict__ tgt, const int* __restrict__ tgt_len,
    float* __restrict__ loss_ws)
{
    const int b = blockIdx.x, lane = threadIdx.x;
    const int Tin = in_len[b], Lt = tgt_len[b];
    const int ext_len = 2 * Lt + 1;
    const int* tg = tgt + b * CT_S;
    const int s0 = 4 * lane, s1 = s0 + 1, s3 = s0 + 3;
    const int i1 = min((s1 - 1) >> 1, CT_S - 1);
    const int i3 = min((s3 - 1) >> 1, CT_S - 1);
    const int c1 = tg[i1], c3 = tg[i3];
    const bool skip1 = (s1 >= 3) && (s1 < CT_Se) && (c1 != tg[max(i1 - 1, 0)]);
    const bool skip3 = (s3 >= 3) && (s3 < CT_Se) && (c3 != tg[max(i3 - 1, 0)]);
    const bool v0 = s0 < ext_len, v1 = s1 < ext_len;
    const bool v2 = (s0 + 2) < ext_len, v3 = s3 < ext_len;
    const float* row0 = logp + (long long)b * CT_V;
    const long long stride = (long long)CT_B * CT_V;
    float a0 = NEGF, a1 = NEGF, a2 = NEGF, a3 = NEGF;
    if (lane == 0) {
        a0 = row0[1] * LOG2E;
        if (ext_len > 1) a1 = row0[c1] * LOG2E;
    }
    float3 E0, E1, E2, E3;
    auto ld = [&](float3& e, int t) {
        int tt = min(t, CT_T - 1);
        const float* r = row0 + (long long)tt * stride;
        e.x = r[1] * LOG2E; e.y = r[c1] * LOG2E; e.z = r[c3] * LOG2E;
    };
    auto step = [&](const float3& e) {
        float pa3 = __shfl_up(a3, 1);
        if (lane == 0) pa3 = NEGF;
        float z1 = skip1 ? pa3 : NEGF;
        float z3 = skip3 ? a1 : NEGF;
        float n0 = v0 ? lae2_b2(a0, pa3)    + e.x : NEGF;
        float n1 = v1 ? lae3_b2(a1, a0, z1) + e.y : NEGF;
        float n2 = v2 ? lae2_b2(a2, a1)     + e.x : NEGF;
        float n3 = v3 ? lae3_b2(a3, a2, z3) + e.z : NEGF;
        a0 = n0; a1 = n1; a2 = n2; a3 = n3;
    };
    ld(E0, 1); ld(E1, 2); ld(E2, 3); ld(E3, 4);
    for (int t = 1; t < Tin; t += 4) {
        step(E0); ld(E0, t + 4);
        if (t + 1 < Tin) { step(E1); ld(E1, t + 5); }
        if (t + 2 < Tin) { step(E2); ld(E2, t + 6); }
        if (t + 3 < Tin) { step(E3); ld(E3, t + 7); }
    }
    const int last = 2 * Lt, prev = max(last - 1, 0);
    const int lr = last & 3, lidx = last >> 2;
    float av = (lr == 0) ? a0 : (lr == 1) ? a1 : (lr == 2) ? a2 : a3;
    float a_last = __shfl(av, lidx);
    const int pr = prev & 3, pidx = prev >> 2;
    float pv = (pr == 0) ? a0 : (pr == 1) ? a1 : (pr == 2) ? a2 : a3;
    float a_prev = __shfl(pv, pidx);
    float loglik = lae2_b2(a_last, a_prev) * LN2;
    float loss = (loglik < 0.5f * NEGF) ? 0.0f : -loglik;
    if (lane == 0) loss_ws[b] = loss;
}

__global__ __launch_bounds__(64) void ctc_sum(const float* __restrict__ loss_ws,
                                              float* __restrict__ out)
{
    float v = loss_ws[threadIdx.x];
    #pragma unroll
    for (int o = 32; o > 0; o >>= 1) v += __shfl_down(v, o);
    if (threadIdx.x == 0) out[0] = v;
}

extern "C" void kernel_launch(void* const* d_in, const int* in_sizes, int n_in,
                              void* d_out, int out_size, void* d_ws, size_t ws_size,
                              hipStream_t stream) {
    const float* logp    = (const float*)d_in[0];
    const int*   in_len  = (const int*)d_in[1];
    const int*   tgt     = (const int*)d_in[2];
    const int*   tgt_len = (const int*)d_in[3];
    float* out = (float*)d_out;

    if (ws_size >= WS_NEEDED) {
        unsigned short* em = (unsigned short*)d_ws;
        float* loss_ws = (float*)((char*)d_ws + EM_BYTES);
        hipLaunchKernelGGL(ctc_emit, dim3(CT_T / 4, CT_B), dim3(256), 0, stream,
                           logp, tgt, em);
        hipLaunchKernelGGL(ctc_alpha, dim3(CT_B), dim3(64), 0, stream,
                           in_len, tgt, tgt_len, em, loss_ws);
        hipLaunchKernelGGL(ctc_sum, dim3(1), dim3(64), 0, stream, loss_ws, out);
    } else {
        float* loss_ws = (float*)d_ws;
        hipLaunchKernelGGL(ctc_alpha_fb, dim3(CT_B), dim3(64), 0, stream,
                           logp, in_len, tgt, tgt_len, loss_ws);
        hipLaunchKernelGGL(ctc_sum, dim3(1), dim3(64), 0, stream, loss_ws, out);
    }
}